// Round 5
// baseline (357.855 us; speedup 1.0000x reference)
//
#include <hip/hip_runtime.h>
#include <hip/hip_bf16.h>
#include <math.h>

#define HID 64
#define DT 0.1f
#define MIN_TAU 0.1f
#define TAU_SCALE 9.9f   // MAX_TAU - MIN_TAU

// Augmented weight rows (bf16):
//   rows   0..63  : [W_tau(64) | U_tau(3) | b_tau(1) | pad]  -> tau_raw
//   rows  64..127 : [W_h(64)   | U_h(3)   | b_h(1)   | pad]  -> pre
//   rows 128..191 : [I64(64)   | 0        | 0        | pad]  -> h (bf16-identity passthrough)
// row stride 104 bf16 = 208 B (16B-aligned; b128 reads at 52-word stride ~conflict-free)
#define WSTRIDE 104
#define WROWS   192
#define WELEMS  (WROWS * WSTRIDE)   // 19968 bf16 = 39936 B

typedef __attribute__((ext_vector_type(8))) short bf16x8;
typedef __attribute__((ext_vector_type(4))) float f32x4;

__device__ __forceinline__ short f2bf(float f) {
    union { __hip_bfloat16 b; short s; } c;
    c.b = __float2bfloat16(f);
    return c.s;
}
__device__ __forceinline__ float fast_rcp(float x) { return __builtin_amdgcn_rcpf(x); }
__device__ __forceinline__ float fast_tanh(float x) {
    float e = __expf(2.f * x);
    return fmaf(-2.f, fast_rcp(e + 1.f), 1.f);
}

// ---- kernel 0: convert + pack augmented weights into d_ws ----
__global__ __launch_bounds__(256) void prep_weights(
    const float* __restrict__ W_tau, const float* __restrict__ U_tau,
    const float* __restrict__ b_tau,
    const float* __restrict__ W_h, const float* __restrict__ U_h,
    const float* __restrict__ b_h,
    short* __restrict__ wbf)
{
    const int idx = blockIdx.x * 256 + threadIdx.x;
    if (idx >= WELEMS) return;
    const int row = idx / WSTRIDE;
    const int c = idx - row * WSTRIDE;
    float val = 0.f;
    if (row < 64) {
        const int r = row;
        if (c < 64)       val = W_tau[r * 64 + c];
        else if (c < 67)  val = U_tau[r * 3 + (c - 64)];
        else if (c == 67) val = b_tau[r];
    } else if (row < 128) {
        const int r = row - 64;
        if (c < 64)       val = W_h[r * 64 + c];
        else if (c < 67)  val = U_h[r * 3 + (c - 64)];
        else if (c == 67) val = b_h[r];
    } else {
        val = (c == row - 128) ? 1.0f : 0.f;
    }
    wbf[idx] = f2bf(val);
}

// ---- main kernel: 256 thr = 4 waves; wave = 16 positions; block-tile = 64 positions ----
// GEMM per wave-tile: M=16, N=192 (tau_raw | pre | h), K=96 (h|u|1)
// launch_bounds (256,3): unified reg cap ~170/wave -> acc(48 AGPR) + ~100 VGPR, NO SPILL.
// (round 4's (256,4) cap=128 forced a scratch spill: FETCH 184->964 MB, dur 228->360 us)
__global__ __launch_bounds__(256, 3) void liquid_mfma_kernel(
    const float* __restrict__ h, const float* __restrict__ u,
    const short* __restrict__ wbf,
    const float* __restrict__ W_out, const float* __restrict__ b_out,
    float* __restrict__ h_out, float* __restrict__ v_out, int ntiles)
{
    __shared__ short wlds[WELEMS];

    const int tid = threadIdx.x;
    {   // stage weights: 39936 B as 4992 uint4 (b128 writes, conflict-free)
        const uint4* s = (const uint4*)wbf;
        uint4* d = (uint4*)wlds;
        for (int i = tid; i < WELEMS / 8; i += 256) d[i] = s[i];
    }

    const int lane = tid & 63;
    const int col  = lane & 15;
    const int quad = lane >> 4;
    const int wid  = tid >> 6;

    float wo[3][4];
#pragma unroll
    for (int o = 0; o < 3; ++o)
#pragma unroll
        for (int nt = 0; nt < 4; ++nt)
            wo[o][nt] = W_out[o * 64 + nt * 16 + col];
    const float bo0 = b_out[0], bo1 = b_out[1], bo2 = b_out[2];

    __syncthreads();   // LDS read-only below: no barriers in the tile loop

    const int tstep = gridDim.x;
    int t = blockIdx.x;

    // prefetch regs: h (4x float4) and u (3 scalars, quad 0 only) for the NEXT tile
    float4 pf0, pf1, pf2, pf3;
    float pu0 = 0.f, pu1 = 0.f, pu2 = 0.f;

#define LOADA(TT)                                                              \
    do {                                                                       \
        const unsigned q_ = (unsigned)(TT) * 64u + (unsigned)(wid * 16 + col); \
        const float* hp_ = h + q_ * 64u + (unsigned)(quad * 8);                \
        pf0 = *(const float4*)hp_;                                             \
        pf1 = *(const float4*)(hp_ + 4);                                       \
        pf2 = *(const float4*)(hp_ + 32);                                      \
        pf3 = *(const float4*)(hp_ + 36);                                      \
        if (quad == 0) {                                                       \
            const float* up_ = u + q_ * 3u;                                    \
            pu0 = up_[0]; pu1 = up_[1]; pu2 = up_[2];                          \
        }                                                                      \
    } while (0)

    if (t < ntiles) LOADA(t);

    for (; t < ntiles; t += tstep) {
        const unsigned q0 = (unsigned)t * 64u + (unsigned)(wid * 16);

        // ---- convert prefetched A to bf16 fragments ----
        bf16x8 af0, af1;
        af0[0] = f2bf(pf0.x); af0[1] = f2bf(pf0.y); af0[2] = f2bf(pf0.z); af0[3] = f2bf(pf0.w);
        af0[4] = f2bf(pf1.x); af0[5] = f2bf(pf1.y); af0[6] = f2bf(pf1.z); af0[7] = f2bf(pf1.w);
        af1[0] = f2bf(pf2.x); af1[1] = f2bf(pf2.y); af1[2] = f2bf(pf2.z); af1[3] = f2bf(pf2.w);
        af1[4] = f2bf(pf3.x); af1[5] = f2bf(pf3.y); af1[6] = f2bf(pf3.z); af1[7] = f2bf(pf3.w);

        // augmented K-step fragment: j=64..66 -> u, j=67 -> 1.0
        bf16x8 af2 = (bf16x8)(short)0;
        if (quad == 0) {
            af2[0] = f2bf(pu0); af2[1] = f2bf(pu1); af2[2] = f2bf(pu2);
            af2[3] = f2bf(1.0f);
        }

        // ---- issue next tile's loads early (hide under MFMA + epilogue) ----
        const int tn = t + tstep;
        if (tn < ntiles) LOADA(tn);

        // ---- MFMA ----
        f32x4 acc[12];
#pragma unroll
        for (int nt = 0; nt < 12; ++nt) acc[nt] = (f32x4){0.f, 0.f, 0.f, 0.f};

#pragma unroll
        for (int nt = 0; nt < 8; ++nt) {
            const short* wb = &wlds[(nt * 16 + col) * WSTRIDE + quad * 8];
            acc[nt] = __builtin_amdgcn_mfma_f32_16x16x32_bf16(
                af0, *(const bf16x8*)wb, acc[nt], 0, 0, 0);
            acc[nt] = __builtin_amdgcn_mfma_f32_16x16x32_bf16(
                af1, *(const bf16x8*)(wb + 32), acc[nt], 0, 0, 0);
            acc[nt] = __builtin_amdgcn_mfma_f32_16x16x32_bf16(
                af2, *(const bf16x8*)(wb + 64), acc[nt], 0, 0, 0);
        }
        // identity block (rows 128..191): h passthrough; u/bias K-step is all-zero -> skip
#pragma unroll
        for (int nt = 8; nt < 12; ++nt) {
            const short* wb = &wlds[(nt * 16 + col) * WSTRIDE + quad * 8];
            acc[nt] = __builtin_amdgcn_mfma_f32_16x16x32_bf16(
                af0, *(const bf16x8*)wb, acc[nt], 0, 0, 0);
            acc[nt] = __builtin_amdgcn_mfma_f32_16x16x32_bf16(
                af1, *(const bf16x8*)(wb + 32), acc[nt], 0, 0, 0);
        }

        // ---- epilogue: D[p = quad*4 + r, ch = ntk*16 + col]; hk from acc[8+ntk] ----
#pragma unroll
        for (int r = 0; r < 4; ++r) {
            const unsigned p = q0 + (unsigned)(quad * 4 + r);
            float pv0 = 0.f, pv1 = 0.f, pv2 = 0.f;
#pragma unroll
            for (int ntk = 0; ntk < 4; ++ntk) {
                const float at = acc[ntk][r];       // tau_raw
                const float ap = acc[ntk + 4][r];   // pre
                const float hk = acc[ntk + 8][r];   // h (bf16-rounded passthrough)
                const float sp = fmaxf(at, 0.f) + __logf(1.f + __expf(-fabsf(at)));
                const float tau = fmaf(sp, TAU_SCALE, MIN_TAU);
                const float f = fast_rcp(1.f + __expf(-ap));
                const float hnew = fmaf(DT, f - hk * fast_rcp(tau), hk);
                h_out[p * 64u + (unsigned)(ntk * 16 + col)] = hnew;  // 64B-coalesced groups
                pv0 = fmaf(hnew, wo[0][ntk], pv0);
                pv1 = fmaf(hnew, wo[1][ntk], pv1);
                pv2 = fmaf(hnew, wo[2][ntk], pv2);
            }
#pragma unroll
            for (int s = 1; s < 16; s <<= 1) {
                pv0 += __shfl_xor(pv0, s, 64);
                pv1 += __shfl_xor(pv1, s, 64);
                pv2 += __shfl_xor(pv2, s, 64);
            }
            if (col == 0) {
                v_out[p * 3u + 0u] = fast_tanh(pv0 + bo0);
                v_out[p * 3u + 1u] = fast_tanh(pv1 + bo1);
                v_out[p * 3u + 2u] = fast_tanh(pv2 + bo2);
            }
        }
    }
#undef LOADA
}

extern "C" void kernel_launch(void* const* d_in, const int* in_sizes, int n_in,
                              void* d_out, int out_size, void* d_ws, size_t ws_size,
                              hipStream_t stream) {
    const float* h     = (const float*)d_in[0];
    const float* u     = (const float*)d_in[1];
    const float* W_h   = (const float*)d_in[2];
    const float* U_h   = (const float*)d_in[3];
    const float* b_h   = (const float*)d_in[4];
    const float* W_tau = (const float*)d_in[5];
    const float* U_tau = (const float*)d_in[6];
    const float* b_tau = (const float*)d_in[7];
    const float* W_out = (const float*)d_in[8];
    const float* b_out = (const float*)d_in[9];

    const int total = in_sizes[0] / HID;   // B*N positions (1048576)
    float* h_out = (float*)d_out;
    float* v_out = h_out + (size_t)total * HID;

    short* wbf = (short*)d_ws;   // 39936 B of scratch

    prep_weights<<<(WELEMS + 255) / 256, 256, 0, stream>>>(
        W_tau, U_tau, b_tau, W_h, U_h, b_h, wbf);

    const int ntiles = total / 64;   // 64 positions per block-tile
    const int grid = 1024;           // 16 tiles per block, grid-stride
    liquid_mfma_kernel<<<grid, 256, 0, stream>>>(
        h, u, wbf, W_out, b_out, h_out, v_out, ntiles);
}

// Round 6
// 147.552 us; speedup vs baseline: 2.4253x; 2.4253x over previous
//
#include <hip/hip_runtime.h>
#include <hip/hip_bf16.h>
#include <math.h>

#define HID 64
#define DT 0.1f
#define MIN_TAU 0.1f
#define TAU_SCALE 9.9f   // MAX_TAU - MIN_TAU

// Augmented weight rows (bf16):
//   rows   0..63  : [W_tau(64) | U_tau(3) | b_tau(1) | pad]  -> tau_raw
//   rows  64..127 : [W_h(64)   | U_h(3)   | b_h(1)   | pad]  -> pre
//   rows 128..191 : [I64(64)   | 0        | 0        | pad]  -> h (bf16-identity passthrough)
// row stride 104 bf16 = 208 B (16B-aligned; b128 reads at 52-word stride ~conflict-free)
#define WSTRIDE 104
#define WROWS   192
#define WELEMS  (WROWS * WSTRIDE)   // 19968 bf16 = 39936 B

typedef __attribute__((ext_vector_type(8))) short bf16x8;
typedef __attribute__((ext_vector_type(4))) float f32x4;

__device__ __forceinline__ short f2bf(float f) {
    union { __hip_bfloat16 b; short s; } c;
    c.b = __float2bfloat16(f);
    return c.s;
}
__device__ __forceinline__ float fast_rcp(float x) { return __builtin_amdgcn_rcpf(x); }
__device__ __forceinline__ float fast_tanh(float x) {
    float e = __expf(2.f * x);
    return fmaf(-2.f, fast_rcp(e + 1.f), 1.f);
}

// ---- kernel 0: convert + pack augmented weights into d_ws ----
__global__ __launch_bounds__(256) void prep_weights(
    const float* __restrict__ W_tau, const float* __restrict__ U_tau,
    const float* __restrict__ b_tau,
    const float* __restrict__ W_h, const float* __restrict__ U_h,
    const float* __restrict__ b_h,
    short* __restrict__ wbf)
{
    const int idx = blockIdx.x * 256 + threadIdx.x;
    if (idx >= WELEMS) return;
    const int row = idx / WSTRIDE;
    const int c = idx - row * WSTRIDE;
    float val = 0.f;
    if (row < 64) {
        const int r = row;
        if (c < 64)       val = W_tau[r * 64 + c];
        else if (c < 67)  val = U_tau[r * 3 + (c - 64)];
        else if (c == 67) val = b_tau[r];
    } else if (row < 128) {
        const int r = row - 64;
        if (c < 64)       val = W_h[r * 64 + c];
        else if (c < 67)  val = U_h[r * 3 + (c - 64)];
        else if (c == 67) val = b_h[r];
    } else {
        val = (c == row - 128) ? 1.0f : 0.f;
    }
    wbf[idx] = f2bf(val);
}

// ---- main kernel: 256 thr = 4 waves; wave = 16 positions; block-tile = 64 positions ----
// GEMM per wave-tile: M=16, N=192 (tau_raw | pre | h), K=96 (h|u|1)
// Register budget: acc[12]=48 AGPR + ~130 VGPR => natural demand ~190.
// (256,2) caps at 256 regs/wave -> NO SPILL (rounds 4/5 proved caps of 128/170 spill:
//  FETCH exploded 184->964/521 MB and dur regressed 228->360/385 us).
__global__ __launch_bounds__(256, 2) void liquid_mfma_kernel(
    const float* __restrict__ h, const float* __restrict__ u,
    const short* __restrict__ wbf,
    const float* __restrict__ W_out, const float* __restrict__ b_out,
    float* __restrict__ h_out, float* __restrict__ v_out, int ntiles)
{
    __shared__ short wlds[WELEMS];

    const int tid = threadIdx.x;
    {   // stage weights: 39936 B as 4992 uint4 (b128 writes, conflict-free)
        const uint4* s = (const uint4*)wbf;
        uint4* d = (uint4*)wlds;
        for (int i = tid; i < WELEMS / 8; i += 256) d[i] = s[i];
    }

    const int lane = tid & 63;
    const int col  = lane & 15;
    const int quad = lane >> 4;
    const int wid  = tid >> 6;

    float wo[3][4];
#pragma unroll
    for (int o = 0; o < 3; ++o)
#pragma unroll
        for (int nt = 0; nt < 4; ++nt)
            wo[o][nt] = W_out[o * 64 + nt * 16 + col];
    // per-lane output bias for the lane-select v store (col 0->b0, 1->b1, 2->b2)
    const float bo_sel = (col == 0) ? b_out[0] : ((col == 1) ? b_out[1] : b_out[2]);

    __syncthreads();   // LDS read-only below: no barriers in the tile loop

    const int tstep = gridDim.x;
    int t = blockIdx.x;

    // prefetch regs: h (4x float4) and u (3 scalars, quad 0 only) for the NEXT tile
    float4 pf0, pf1, pf2, pf3;
    float pu0 = 0.f, pu1 = 0.f, pu2 = 0.f;

#define LOADA(TT)                                                              \
    do {                                                                       \
        const unsigned q_ = (unsigned)(TT) * 64u + (unsigned)(wid * 16 + col); \
        const float* hp_ = h + q_ * 64u + (unsigned)(quad * 8);                \
        pf0 = *(const float4*)hp_;                                             \
        pf1 = *(const float4*)(hp_ + 4);                                       \
        pf2 = *(const float4*)(hp_ + 32);                                      \
        pf3 = *(const float4*)(hp_ + 36);                                      \
        if (quad == 0) {                                                       \
            const float* up_ = u + q_ * 3u;                                    \
            pu0 = up_[0]; pu1 = up_[1]; pu2 = up_[2];                          \
        }                                                                      \
    } while (0)

    if (t < ntiles) LOADA(t);

    for (; t < ntiles; t += tstep) {
        const unsigned q0 = (unsigned)t * 64u + (unsigned)(wid * 16);

        // ---- convert prefetched A to bf16 fragments ----
        bf16x8 af0, af1;
        af0[0] = f2bf(pf0.x); af0[1] = f2bf(pf0.y); af0[2] = f2bf(pf0.z); af0[3] = f2bf(pf0.w);
        af0[4] = f2bf(pf1.x); af0[5] = f2bf(pf1.y); af0[6] = f2bf(pf1.z); af0[7] = f2bf(pf1.w);
        af1[0] = f2bf(pf2.x); af1[1] = f2bf(pf2.y); af1[2] = f2bf(pf2.z); af1[3] = f2bf(pf2.w);
        af1[4] = f2bf(pf3.x); af1[5] = f2bf(pf3.y); af1[6] = f2bf(pf3.z); af1[7] = f2bf(pf3.w);

        // augmented K-step fragment: j=64..66 -> u, j=67 -> 1.0
        bf16x8 af2 = (bf16x8)(short)0;
        if (quad == 0) {
            af2[0] = f2bf(pu0); af2[1] = f2bf(pu1); af2[2] = f2bf(pu2);
            af2[3] = f2bf(1.0f);
        }

        // ---- issue next tile's loads early (hide under MFMA + epilogue) ----
        const int tn = t + tstep;
        if (tn < ntiles) LOADA(tn);

        // ---- MFMA ----
        f32x4 acc[12];
#pragma unroll
        for (int nt = 0; nt < 12; ++nt) acc[nt] = (f32x4){0.f, 0.f, 0.f, 0.f};

#pragma unroll
        for (int nt = 0; nt < 8; ++nt) {
            const short* wb = &wlds[(nt * 16 + col) * WSTRIDE + quad * 8];
            acc[nt] = __builtin_amdgcn_mfma_f32_16x16x32_bf16(
                af0, *(const bf16x8*)wb, acc[nt], 0, 0, 0);
            acc[nt] = __builtin_amdgcn_mfma_f32_16x16x32_bf16(
                af1, *(const bf16x8*)(wb + 32), acc[nt], 0, 0, 0);
            acc[nt] = __builtin_amdgcn_mfma_f32_16x16x32_bf16(
                af2, *(const bf16x8*)(wb + 64), acc[nt], 0, 0, 0);
        }
        // identity block (rows 128..191): h passthrough; u/bias K-step is all-zero -> skip
#pragma unroll
        for (int nt = 8; nt < 12; ++nt) {
            const short* wb = &wlds[(nt * 16 + col) * WSTRIDE + quad * 8];
            acc[nt] = __builtin_amdgcn_mfma_f32_16x16x32_bf16(
                af0, *(const bf16x8*)wb, acc[nt], 0, 0, 0);
            acc[nt] = __builtin_amdgcn_mfma_f32_16x16x32_bf16(
                af1, *(const bf16x8*)(wb + 32), acc[nt], 0, 0, 0);
        }

        // ---- epilogue: D[p = quad*4 + r, ch = ntk*16 + col]; hk from acc[8+ntk] ----
#pragma unroll
        for (int r = 0; r < 4; ++r) {
            const unsigned p = q0 + (unsigned)(quad * 4 + r);
            float pv0 = 0.f, pv1 = 0.f, pv2 = 0.f;
#pragma unroll
            for (int ntk = 0; ntk < 4; ++ntk) {
                const float at = acc[ntk][r];       // tau_raw
                const float ap = acc[ntk + 4][r];   // pre
                const float hk = acc[ntk + 8][r];   // h (bf16-rounded passthrough)
                const float sp = fmaxf(at, 0.f) + __logf(1.f + __expf(-fabsf(at)));
                const float tau = fmaf(sp, TAU_SCALE, MIN_TAU);
                const float f = fast_rcp(1.f + __expf(-ap));
                const float hnew = fmaf(DT, f - hk * fast_rcp(tau), hk);
                h_out[p * 64u + (unsigned)(ntk * 16 + col)] = hnew;  // 64B-coalesced groups
                pv0 = fmaf(hnew, wo[0][ntk], pv0);
                pv1 = fmaf(hnew, wo[1][ntk], pv1);
                pv2 = fmaf(hnew, wo[2][ntk], pv2);
            }
#pragma unroll
            for (int s = 1; s < 16; s <<= 1) {
                pv0 += __shfl_xor(pv0, s, 64);
                pv1 += __shfl_xor(pv1, s, 64);
                pv2 += __shfl_xor(pv2, s, 64);
            }
            // lane-select store: lanes col 0..2 each store one channel (1 tanh/lane)
            const float pv = (col == 0) ? pv0 : ((col == 1) ? pv1 : pv2);
            if (col < 3)
                v_out[p * 3u + (unsigned)col] = fast_tanh(pv + bo_sel);
        }
    }
#undef LOADA
}

extern "C" void kernel_launch(void* const* d_in, const int* in_sizes, int n_in,
                              void* d_out, int out_size, void* d_ws, size_t ws_size,
                              hipStream_t stream) {
    const float* h     = (const float*)d_in[0];
    const float* u     = (const float*)d_in[1];
    const float* W_h   = (const float*)d_in[2];
    const float* U_h   = (const float*)d_in[3];
    const float* b_h   = (const float*)d_in[4];
    const float* W_tau = (const float*)d_in[5];
    const float* U_tau = (const float*)d_in[6];
    const float* b_tau = (const float*)d_in[7];
    const float* W_out = (const float*)d_in[8];
    const float* b_out = (const float*)d_in[9];

    const int total = in_sizes[0] / HID;   // B*N positions (1048576)
    float* h_out = (float*)d_out;
    float* v_out = h_out + (size_t)total * HID;

    short* wbf = (short*)d_ws;   // 39936 B of scratch

    prep_weights<<<(WELEMS + 255) / 256, 256, 0, stream>>>(
        W_tau, U_tau, b_tau, W_h, U_h, b_h, wbf);

    const int ntiles = total / 64;   // 64 positions per block-tile
    const int grid = 1024;           // 16 tiles per block, grid-stride
    liquid_mfma_kernel<<<grid, 256, 0, stream>>>(
        h, u, wbf, W_out, b_out, h_out, v_out, ntiles);
}

// Round 7
// 140.182 us; speedup vs baseline: 2.5528x; 1.0526x over previous
//
#include <hip/hip_runtime.h>
#include <hip/hip_bf16.h>
#include <math.h>

#define HID 64
#define DT 0.1f
#define MIN_TAU 0.1f
#define TAU_SCALE 9.9f   // MAX_TAU - MIN_TAU

// Augmented weight rows (bf16), K-major per output row:
//   rows   0..63  : [W_tau(64) | U_tau(3) | b_tau(1) | 0-pad]  -> tau_raw
//   rows  64..127 : [W_h(64)   | U_h(3)   | b_h(1)   | 0-pad]  -> pre
// row stride 104 bf16 = 208 B (16B-aligned for b128-class loads)
#define WSTRIDE 104
#define WROWS   128
#define WELEMS  (WROWS * WSTRIDE)   // 13312 bf16 = 26624 B

typedef __attribute__((ext_vector_type(8))) short bf16x8;
typedef __attribute__((ext_vector_type(4))) float f32x4;

__device__ __forceinline__ short f2bf(float f) {
    union { __hip_bfloat16 b; short s; } c;
    c.b = __float2bfloat16(f);
    return c.s;
}
__device__ __forceinline__ float fast_rcp(float x) { return __builtin_amdgcn_rcpf(x); }
__device__ __forceinline__ float fast_tanh(float x) {
    float e = __expf(2.f * x);
    return fmaf(-2.f, fast_rcp(e + 1.f), 1.f);
}

// ---- kernel 0: convert + pack augmented weights into d_ws ----
__global__ __launch_bounds__(256) void prep_weights(
    const float* __restrict__ W_tau, const float* __restrict__ U_tau,
    const float* __restrict__ b_tau,
    const float* __restrict__ W_h, const float* __restrict__ U_h,
    const float* __restrict__ b_h,
    short* __restrict__ wbf)
{
    const int idx = blockIdx.x * 256 + threadIdx.x;
    if (idx >= WELEMS) return;
    const int row = idx / WSTRIDE;
    const int c = idx - row * WSTRIDE;
    float val = 0.f;
    if (row < 64) {
        const int r = row;
        if (c < 64)       val = W_tau[r * 64 + c];
        else if (c < 67)  val = U_tau[r * 3 + (c - 64)];
        else if (c == 67) val = b_tau[r];
    } else {
        const int r = row - 64;
        if (c < 64)       val = W_h[r * 64 + c];
        else if (c < 67)  val = U_h[r * 3 + (c - 64)];
        else if (c == 67) val = b_h[r];
    }
    wbf[idx] = f2bf(val);
}

// ---- main kernel: 256 thr = 4 independent waves; wave = 16 positions/tile ----
// GEMM per wave-tile: M=16, N=192 (tau_raw | pre | h-identity), K=96 (h|u|1).
// ALL B-fragments live in registers (hoisted once per block): the inner loop has
// ZERO LDS traffic. No __shared__, no __syncthreads.
// Register budget: 24 B-frags (96 VGPR) + 2 id-frags (8) + acc[12] (48) + ~50 misc
// ~= 200 < 256 -> (256,2) cap, no spill (r4/r5 proved caps 128/170 spill).
__global__ __launch_bounds__(256, 2) void liquid_mfma_kernel(
    const float* __restrict__ h, const float* __restrict__ u,
    const short* __restrict__ wbf,
    const float* __restrict__ W_out, const float* __restrict__ b_out,
    float* __restrict__ h_out, float* __restrict__ v_out, int ntiles)
{
    const int tid  = threadIdx.x;
    const int lane = tid & 63;
    const int col  = lane & 15;
    const int quad = lane >> 4;
    const int wid  = tid >> 6;

    // ---- hoist B-fragments into registers (loop-invariant) ----
    // bw[nt][ks]: lane holds Wcat[n = nt*16+col][k = ks*32 + quad*8 + e]
    bf16x8 bw[8][3];
#pragma unroll
    for (int nt = 0; nt < 8; ++nt)
#pragma unroll
        for (int ks = 0; ks < 3; ++ks)
            bw[nt][ks] = *(const bf16x8*)&wbf[(nt * 16 + col) * WSTRIDE + ks * 32 + quad * 8];

    // identity B-fragments (h passthrough): value 1.0bf16 where k-index matches
    //   idA: quad*8+e == col      (serves acc[8] with af0, acc[10] with af1)
    //   idB: quad*8+e == col+16   (serves acc[9] with af0, acc[11] with af1)
    bf16x8 idA, idB;
#pragma unroll
    for (int e = 0; e < 8; ++e) {
        idA[e] = (quad * 8 + e == col)      ? (short)0x3F80 : (short)0;
        idB[e] = (quad * 8 + e == col + 16) ? (short)0x3F80 : (short)0;
    }

    float wo[3][4];
#pragma unroll
    for (int o = 0; o < 3; ++o)
#pragma unroll
        for (int nt = 0; nt < 4; ++nt)
            wo[o][nt] = W_out[o * 64 + nt * 16 + col];
    // per-lane output bias for the lane-select v store (col 0->b0, 1->b1, 2->b2)
    const float bo_sel = (col == 0) ? b_out[0] : ((col == 1) ? b_out[1] : b_out[2]);

    const int tstep = gridDim.x;
    int t = blockIdx.x;

    // prefetch regs: h (4x float4) and u (3 scalars, quad 0 only) for the NEXT tile
    float4 pf0, pf1, pf2, pf3;
    float pu0 = 0.f, pu1 = 0.f, pu2 = 0.f;

#define LOADA(TT)                                                              \
    do {                                                                       \
        const unsigned q_ = (unsigned)(TT) * 64u + (unsigned)(wid * 16 + col); \
        const float* hp_ = h + q_ * 64u + (unsigned)(quad * 8);                \
        pf0 = *(const float4*)hp_;                                             \
        pf1 = *(const float4*)(hp_ + 4);                                       \
        pf2 = *(const float4*)(hp_ + 32);                                      \
        pf3 = *(const float4*)(hp_ + 36);                                      \
        if (quad == 0) {                                                       \
            const float* up_ = u + q_ * 3u;                                    \
            pu0 = up_[0]; pu1 = up_[1]; pu2 = up_[2];                          \
        }                                                                      \
    } while (0)

    if (t < ntiles) LOADA(t);

    for (; t < ntiles; t += tstep) {
        const unsigned q0 = (unsigned)t * 64u + (unsigned)(wid * 16);

        // ---- convert prefetched A to bf16 fragments ----
        bf16x8 af0, af1;
        af0[0] = f2bf(pf0.x); af0[1] = f2bf(pf0.y); af0[2] = f2bf(pf0.z); af0[3] = f2bf(pf0.w);
        af0[4] = f2bf(pf1.x); af0[5] = f2bf(pf1.y); af0[6] = f2bf(pf1.z); af0[7] = f2bf(pf1.w);
        af1[0] = f2bf(pf2.x); af1[1] = f2bf(pf2.y); af1[2] = f2bf(pf2.z); af1[3] = f2bf(pf2.w);
        af1[4] = f2bf(pf3.x); af1[5] = f2bf(pf3.y); af1[6] = f2bf(pf3.z); af1[7] = f2bf(pf3.w);

        // augmented K-step fragment: j=64..66 -> u, j=67 -> 1.0
        bf16x8 af2 = (bf16x8)(short)0;
        if (quad == 0) {
            af2[0] = f2bf(pu0); af2[1] = f2bf(pu1); af2[2] = f2bf(pu2);
            af2[3] = f2bf(1.0f);
        }

        // ---- issue next tile's loads early (hide under MFMA + epilogue) ----
        const int tn = t + tstep;
        if (tn < ntiles) LOADA(tn);

        // ---- MFMA: pure register operands, no memory ops ----
        f32x4 acc[12];
#pragma unroll
        for (int nt = 0; nt < 12; ++nt) acc[nt] = (f32x4){0.f, 0.f, 0.f, 0.f};

#pragma unroll
        for (int nt = 0; nt < 8; ++nt) {
            acc[nt] = __builtin_amdgcn_mfma_f32_16x16x32_bf16(af0, bw[nt][0], acc[nt], 0, 0, 0);
            acc[nt] = __builtin_amdgcn_mfma_f32_16x16x32_bf16(af1, bw[nt][1], acc[nt], 0, 0, 0);
            acc[nt] = __builtin_amdgcn_mfma_f32_16x16x32_bf16(af2, bw[nt][2], acc[nt], 0, 0, 0);
        }
        // h passthrough: channels 0..15 / 16..31 from af0, 32..47 / 48..63 from af1
        acc[8]  = __builtin_amdgcn_mfma_f32_16x16x32_bf16(af0, idA, acc[8],  0, 0, 0);
        acc[9]  = __builtin_amdgcn_mfma_f32_16x16x32_bf16(af0, idB, acc[9],  0, 0, 0);
        acc[10] = __builtin_amdgcn_mfma_f32_16x16x32_bf16(af1, idA, acc[10], 0, 0, 0);
        acc[11] = __builtin_amdgcn_mfma_f32_16x16x32_bf16(af1, idB, acc[11], 0, 0, 0);

        // ---- epilogue: D[p = quad*4 + r, ch = ntk*16 + col]; hk from acc[8+ntk] ----
#pragma unroll
        for (int r = 0; r < 4; ++r) {
            const unsigned p = q0 + (unsigned)(quad * 4 + r);
            float pv0 = 0.f, pv1 = 0.f, pv2 = 0.f;
#pragma unroll
            for (int ntk = 0; ntk < 4; ++ntk) {
                const float at = acc[ntk][r];       // tau_raw
                const float ap = acc[ntk + 4][r];   // pre
                const float hk = acc[ntk + 8][r];   // h (bf16-rounded passthrough)
                const float sp = fmaxf(at, 0.f) + __logf(1.f + __expf(-fabsf(at)));
                const float tau = fmaf(sp, TAU_SCALE, MIN_TAU);
                const float f = fast_rcp(1.f + __expf(-ap));
                const float hnew = fmaf(DT, f - hk * fast_rcp(tau), hk);
                h_out[p * 64u + (unsigned)(ntk * 16 + col)] = hnew;  // 64B-coalesced groups
                pv0 = fmaf(hnew, wo[0][ntk], pv0);
                pv1 = fmaf(hnew, wo[1][ntk], pv1);
                pv2 = fmaf(hnew, wo[2][ntk], pv2);
            }
#pragma unroll
            for (int s = 1; s < 16; s <<= 1) {
                pv0 += __shfl_xor(pv0, s, 64);
                pv1 += __shfl_xor(pv1, s, 64);
                pv2 += __shfl_xor(pv2, s, 64);
            }
            // lane-select store: lanes col 0..2 each store one channel (1 tanh/lane)
            const float pv = (col == 0) ? pv0 : ((col == 1) ? pv1 : pv2);
            if (col < 3)
                v_out[p * 3u + (unsigned)col] = fast_tanh(pv + bo_sel);
        }
    }
#undef LOADA
}

extern "C" void kernel_launch(void* const* d_in, const int* in_sizes, int n_in,
                              void* d_out, int out_size, void* d_ws, size_t ws_size,
                              hipStream_t stream) {
    const float* h     = (const float*)d_in[0];
    const float* u     = (const float*)d_in[1];
    const float* W_h   = (const float*)d_in[2];
    const float* U_h   = (const float*)d_in[3];
    const float* b_h   = (const float*)d_in[4];
    const float* W_tau = (const float*)d_in[5];
    const float* U_tau = (const float*)d_in[6];
    const float* b_tau = (const float*)d_in[7];
    const float* W_out = (const float*)d_in[8];
    const float* b_out = (const float*)d_in[9];

    const int total = in_sizes[0] / HID;   // B*N positions (1048576)
    float* h_out = (float*)d_out;
    float* v_out = h_out + (size_t)total * HID;

    short* wbf = (short*)d_ws;   // 26624 B of scratch

    prep_weights<<<(WELEMS + 255) / 256, 256, 0, stream>>>(
        W_tau, U_tau, b_tau, W_h, U_h, b_h, wbf);

    const int ntiles = total / 64;   // 64 positions per block-tile
    const int grid = 1024;           // 16 tiles per block, grid-stride
    liquid_mfma_kernel<<<grid, 256, 0, stream>>>(
        h, u, wbf, W_out, b_out, h_out, v_out, ntiles);
}